// Round 1
// 813.215 us; speedup vs baseline: 1.2394x; 1.2394x over previous
//
#include <hip/hip_runtime.h>

// Problem constants: B=8, C=128, H=W=256, L=3, K=5, fp32.
#define BB 8
#define CC 128
#define HH 256
#define WW 256

// ---------------------------------------------------------------------------
// Forward level (levels 1,2 only now): fused Haar WT + depthwise 5x5 + wscale.
// Unchanged from verified kernel.
//   in    : (B*C, H, W)
//   wconv : (4*C, 25), wsc : (4*C)
//   tag   : (B*C, 4, H/2, W/2)
//   rawLL : (B*C, H/2, W/2) or nullptr
// ---------------------------------------------------------------------------
template <int H, int W>
__global__ __launch_bounds__(256) void fwd_level_kernel(
    const float* __restrict__ in,
    const float* __restrict__ wconv,
    const float* __restrict__ wsc,
    float* __restrict__ tag,
    float* __restrict__ rawLL)
{
    constexpr int hh = H / 2, ww = W / 2;
    const int bc  = blockIdx.z;
    const int c   = bc % CC;
    const int ti0 = blockIdx.y * 16;
    const int tj0 = blockIdx.x * 16;
    const int tid = threadIdx.x;

    __shared__ float sb[4][20][20];
    __shared__ float wg[4][25];
    __shared__ float wsl[4];

    if (tid < 100) {
        int k = tid / 25, t = tid % 25;
        wg[k][t] = wconv[(c * 4 + k) * 25 + t];
    }
    if (tid < 4) wsl[tid] = wsc[c * 4 + tid];

    const float* inb = in + (size_t)bc * H * W;

    for (int idx = tid; idx < 400; idx += 256) {
        int r = idx / 20, q = idx % 20;
        int si = ti0 - 2 + r, sj = tj0 - 2 + q;
        float c0 = 0.f, c1 = 0.f, c2 = 0.f, c3 = 0.f;
        if (si >= 0 && si < hh && sj >= 0 && sj < ww) {
            const float* p = inb + (size_t)(2 * si) * W + 2 * sj;
            float x00 = p[0], x01 = p[1], x10 = p[W], x11 = p[W + 1];
            c0 = 0.5f * (x00 + x01 + x10 + x11);
            c1 = 0.5f * (x00 + x01 - x10 - x11);
            c2 = 0.5f * (x00 - x01 + x10 - x11);
            c3 = 0.5f * (x00 - x01 - x10 + x11);
        }
        sb[0][r][q] = c0; sb[1][r][q] = c1; sb[2][r][q] = c2; sb[3][r][q] = c3;
    }
    __syncthreads();

    const int ty = tid / 16, tx = tid % 16;
    const int i = ti0 + ty, j = tj0 + tx;

    float outv[4];
#pragma unroll
    for (int k = 0; k < 4; ++k) {
        float acc = 0.f;
#pragma unroll
        for (int u = 0; u < 5; ++u)
#pragma unroll
            for (int v = 0; v < 5; ++v)
                acc += sb[k][ty + u][tx + v] * wg[k][u * 5 + v];
        outv[k] = wsl[k] * acc;
    }

    const size_t plane = (size_t)hh * ww;
    const size_t tbase = (size_t)bc * 4 * plane + (size_t)i * ww + j;
#pragma unroll
    for (int k = 0; k < 4; ++k)
        tag[tbase + (size_t)k * plane] = outv[k];

    if (rawLL)
        rawLL[(size_t)bc * plane + (size_t)i * ww + j] = sb[0][ty + 2][tx + 2];
}

// ---------------------------------------------------------------------------
// ll0: rawLL0 = Haar-LL(x). Pure streaming, float4 in/out.
//   x  : (B*C, 256, 256) -> ll : (B*C, 128, 128)
// Each thread: 4 consecutive LL outputs (reads 2x8 x-floats, writes float4).
// ---------------------------------------------------------------------------
__global__ __launch_bounds__(256) void ll0_kernel(
    const float* __restrict__ x, float* __restrict__ ll)
{
    int gid = blockIdx.x * 256 + threadIdx.x;    // 1024*4096 threads total
    int t  = gid & 4095;                          // 4096 threads per bc plane
    int bc = gid >> 12;
    int i  = t >> 5;                              // LL row 0..127
    int j4 = (t & 31) << 2;                       // LL col start (x4)
    const float* p = x + (size_t)bc * 65536 + (size_t)(2 * i) * 256 + 2 * j4;
    float4 a0 = *(const float4*)p;
    float4 a1 = *(const float4*)(p + 4);
    float4 b0 = *(const float4*)(p + 256);
    float4 b1 = *(const float4*)(p + 260);
    float4 r;
    r.x = 0.5f * (a0.x + a0.y + b0.x + b0.y);
    r.y = 0.5f * (a0.z + a0.w + b0.z + b0.w);
    r.z = 0.5f * (a1.x + a1.y + b1.x + b1.y);
    r.w = 0.5f * (a1.z + a1.w + b1.z + b1.w);
    *(float4*)(ll + (size_t)bc * 16384 + i * 128 + j4) = r;
}

// ---------------------------------------------------------------------------
// final2: fully fused output kernel. Per (b,c) 32x32 output tile:
//   - load x tile 40x40 (halo 4 for both base conv and level-0 coeff halo)
//   - recompute level-0 Haar coeffs (20x20 x 4 bands) in LDS  [kills tag0]
//   - depthwise 5x5 + wscale on the 4 bands -> scv (16x16 x 4)
//   - iwt2 (tag2 4x4 tile) -> ll2up 8x8 ; iwt1 (tag1 8x8 tile) -> ll1up 16x16
//   - base 5x5 conv from sx (register-blocked, 4 consecutive rows/thread)
//   - iwt0 + combine + store
// ---------------------------------------------------------------------------
__global__ __launch_bounds__(256) void final2_kernel(
    const float* __restrict__ x,          // (B*C, 256, 256)
    const float* __restrict__ tag1,       // (B*C, 4, 64, 64)
    const float* __restrict__ tag2,       // (B*C, 4, 32, 32)
    const float* __restrict__ wconv0,     // (512, 25) level-0
    const float* __restrict__ wsc0,       // (512)
    const float* __restrict__ base_w,     // (C, 25)
    const float* __restrict__ base_b,     // (C)
    const float* __restrict__ base_scale, // (C)
    float* __restrict__ out)              // (B*C, 256, 256)
{
    const int bc  = blockIdx.z;
    const int c   = bc % CC;
    const int tY0 = blockIdx.y * 32, tX0 = blockIdx.x * 32;
    const int tid = threadIdx.x;

    __shared__ float sx[40][42];        // x tile, origin (tY0-4, tX0-4)
    __shared__ float scf[4][20][22];    // level-0 coeff halo tile
    __shared__ float scv[4][16][17];    // wscale*conv output per band
    __shared__ float sll1[16][17];      // upsampled LL from level 1
    __shared__ float st1[4][8][9];      // tag1 tile
    __shared__ float sll2[8][9];        // upsampled LL from level 2
    __shared__ float wb[25];
    __shared__ float w0[4][25];
    __shared__ float wsl[4];
    __shared__ float sbias, sscale;

    // ---- loads ----
    if (tid < 25) wb[tid] = base_w[c * 25 + tid];
    if (tid >= 32 && tid < 132) {
        int t = tid - 32;
        w0[t / 25][t % 25] = wconv0[(c * 4 + t / 25) * 25 + t % 25];
    }
    if (tid >= 160 && tid < 164) wsl[tid - 160] = wsc0[c * 4 + (tid - 160)];
    if (tid == 255) { sbias = base_b[c]; sscale = base_scale[c]; }

    const float* xb = x + (size_t)bc * (HH * WW);
    for (int idx = tid; idx < 1600; idx += 256) {
        int r = idx / 40, q = idx - r * 40;
        int Y = tY0 - 4 + r, X = tX0 - 4 + q;
        sx[r][q] = (Y >= 0 && Y < HH && X >= 0 && X < WW)
                       ? xb[Y * WW + X] : 0.f;
    }

    const int t1r0 = tY0 >> 2, t1c0 = tX0 >> 2;   // tag1 tile origin (64x64)
    const float* t1b = tag1 + (size_t)bc * 4 * 4096;
    {
        int k = tid >> 6, t = tid & 63, r = t >> 3, q = t & 7;
        st1[k][r][q] = t1b[k * 4096 + (t1r0 + r) * 64 + (t1c0 + q)];
    }

    // iwt2 directly from global (tiny, L1-resident): ll2up 8x8 tile
    const int t2r0 = tY0 >> 3, t2c0 = tX0 >> 3;   // tag2 tile origin (32x32)
    const float* t2b = tag2 + (size_t)bc * 4 * 1024;
    if (tid < 64) {
        int r = tid >> 3, q = tid & 7;
        const float* p = t2b + (t2r0 + (r >> 1)) * 32 + (t2c0 + (q >> 1));
        float d0 = p[0], d1 = p[1024], d2 = p[2048], d3 = p[3072];
        float ss = (r & 1) ? -1.f : 1.f, tt = (q & 1) ? -1.f : 1.f;
        sll2[r][q] = 0.5f * (d0 + ss * d1 + tt * d2 + ss * tt * d3);
    }
    __syncthreads();   // B1

    // ---- P2: level-0 Haar coeffs + iwt1 ----
    for (int idx = tid; idx < 400; idx += 256) {
        int r = idx / 20, q = idx - r * 20;
        float x00 = sx[2 * r][2 * q],     x01 = sx[2 * r][2 * q + 1];
        float x10 = sx[2 * r + 1][2 * q], x11 = sx[2 * r + 1][2 * q + 1];
        scf[0][r][q] = 0.5f * (x00 + x01 + x10 + x11);
        scf[1][r][q] = 0.5f * (x00 + x01 - x10 - x11);
        scf[2][r][q] = 0.5f * (x00 - x01 + x10 - x11);
        scf[3][r][q] = 0.5f * (x00 - x01 - x10 + x11);
    }
    {
        int ci = tid >> 4, cj = tid & 15;
        int a = ci >> 1, b = cj >> 1;
        float e0 = st1[0][a][b] + sll2[a][b];
        float e1 = st1[1][a][b], e2 = st1[2][a][b], e3 = st1[3][a][b];
        float ss = (ci & 1) ? -1.f : 1.f, tt = (cj & 1) ? -1.f : 1.f;
        sll1[ci][cj] = 0.5f * (e0 + ss * e1 + tt * e2 + ss * tt * e3);
    }
    __syncthreads();   // B2

    // ---- P3a: band convs (4 consecutive rows/thread, sliding window) ----
    {
        int k = tid >> 6, t = tid & 63, g = t >> 4, cx = t & 15;
        float accb[4] = {0.f, 0.f, 0.f, 0.f};
#pragma unroll
        for (int v = 0; v < 5; ++v)
#pragma unroll
            for (int i = 0; i < 8; ++i) {
                float val = scf[k][4 * g + i][cx + v];
#pragma unroll
                for (int r = 0; r < 4; ++r) {
                    int u = i - r;
                    if (u >= 0 && u < 5) accb[r] += val * w0[k][u * 5 + v];
                }
            }
        float wk = wsl[k];
#pragma unroll
        for (int r = 0; r < 4; ++r) scv[k][4 * g + r][cx] = wk * accb[r];
    }

    // ---- P3b: base conv into registers (4 consecutive rows/thread) ----
    const int ty = tid >> 5, tx = tid & 31;       // 8 x 32, rows 4*ty..4*ty+3
    float accx[4] = {0.f, 0.f, 0.f, 0.f};
#pragma unroll
    for (int v = 0; v < 5; ++v)
#pragma unroll
        for (int i = 0; i < 8; ++i) {
            float val = sx[4 * ty + i + 2][tx + v + 2];
#pragma unroll
            for (int r = 0; r < 4; ++r) {
                int u = i - r;
                if (u >= 0 && u < 5) accx[r] += val * wb[u * 5 + v];
            }
        }
    __syncthreads();   // B3

    // ---- P4: iwt0 + combine + store ----
    float* ob = out + (size_t)bc * (HH * WW);
    const int Ybase = tY0 + 4 * ty;
    const int cx = tx >> 1;
    const float sbn = (tx & 1) ? -1.f : 1.f;
#pragma unroll
    for (int half = 0; half < 2; ++half) {
        int cy = 2 * ty + half;
        float c0 = scv[0][cy][cx] + sll1[cy][cx];
        float c1 = scv[1][cy][cx];
        float c2 = scv[2][cy][cx];
        float c3 = scv[3][cy][cx];
        float e = c0 + sbn * c2;
        float o = c1 + sbn * c3;
        float w_even = 0.5f * (e + o);
        float w_odd  = 0.5f * (e - o);
        int r0 = 2 * half;
        ob[(Ybase + r0) * WW + tX0 + tx] =
            sscale * (accx[r0] + sbias) + w_even;
        ob[(Ybase + r0 + 1) * WW + tX0 + tx] =
            sscale * (accx[r0 + 1] + sbias) + w_odd;
    }
}

// ---------------------------------------------------------------------------
extern "C" void kernel_launch(void* const* d_in, const int* in_sizes, int n_in,
                              void* d_out, int out_size, void* d_ws, size_t ws_size,
                              hipStream_t stream)
{
    const float* x          = (const float*)d_in[0];
    // d_in[1] wt_filter, d_in[2] iwt_filter: fixed Haar, hard-coded above.
    const float* base_w     = (const float*)d_in[3];
    const float* base_b     = (const float*)d_in[4];
    const float* base_scale = (const float*)d_in[5];
    const float* wconv      = (const float*)d_in[6];  // (3, 512, 25)
    const float* wscale     = (const float*)d_in[7];  // (3, 512)
    float* out = (float*)d_out;
    float* ws  = (float*)d_ws;

    // Workspace layout (floats):
    float* rawLL0 = ws;                  // 8*128*128*128 = 16,777,216
    float* tag1   = ws + 16777216;       // 8*128*4*64*64 = 16,777,216
    float* rawLL1 = ws + 33554432;       // 8*128*64*64   =  4,194,304
    float* tag2   = ws + 37748736;       // 8*128*4*32*32 =  4,194,304
    // total 41,943,040 floats = 160 MiB

    const dim3 blk(256);
    const int BC = BB * CC;

    // Level-0 LL only (tag0 is recomputed inside final2).
    ll0_kernel<<<dim3(16384), blk, 0, stream>>>(x, rawLL0);

    // Forward levels 1, 2 (unchanged verified kernels).
    fwd_level_kernel<128, 128><<<dim3(4, 4, BC), blk, 0, stream>>>(
        rawLL0, wconv + 512 * 25, wscale + 512, tag1, rawLL1);
    fwd_level_kernel<64, 64><<<dim3(2, 2, BC), blk, 0, stream>>>(
        rawLL1, wconv + 2 * 512 * 25, wscale + 2 * 512, tag2, nullptr);

    // Fully fused: level-0 fwd recompute + iwt2 + iwt1 + iwt0 + base conv.
    final2_kernel<<<dim3(8, 8, BC), blk, 0, stream>>>(
        x, tag1, tag2, wconv, wscale, base_w, base_b, base_scale, out);
}

// Round 2
// 690.473 us; speedup vs baseline: 1.4597x; 1.1778x over previous
//
#include <hip/hip_runtime.h>

// Problem constants: B=8, C=128, H=W=256, L=3, K=5, fp32.
#define BB 8
#define CC 128
#define HH 256
#define WW 256

// ---------------------------------------------------------------------------
// fwd1_fused: level-1 forward directly from x. Staging computes TWO Haar
// levels per coefficient (each level-1 coeff = double butterfly of a 4x4 x
// patch, read as 4 float4s). Kills the ll0 kernel and the rawLL0 round trip.
//   x      : (B*C, 256, 256)
//   wconv  : (512, 25) level-1 weights ; wsc : (512)
//   tag    : (B*C, 4, 64, 64)
//   rawLL1 : (B*C, 64, 64)   raw level-1 LL (input to level 2)
// Grid (2,2,B*C), 256 threads, 32x32 subband outputs per block.
// ---------------------------------------------------------------------------
__global__ __launch_bounds__(256, 4) void fwd1_fused_kernel(
    const float* __restrict__ x,
    const float* __restrict__ wconv,
    const float* __restrict__ wsc,
    float* __restrict__ tag,
    float* __restrict__ rawLL1)
{
    const int bc  = blockIdx.z;
    const int c   = bc % CC;
    const int ti0 = blockIdx.y * 32, tj0 = blockIdx.x * 32;
    const int tid = threadIdx.x;

    __shared__ float sb[4][36][38];   // 36x36 coeff halo; stride 38 (2-way max)
    __shared__ float wg[4][25];
    __shared__ float wsl[4];

    if (tid < 100) { int k = tid / 25, t = tid % 25;
                     wg[k][t] = wconv[(c * 4 + k) * 25 + t]; }
    if (tid < 4) wsl[tid] = wsc[c * 4 + tid];

    const float* xb = x + (size_t)bc * (HH * WW);
    for (int idx = tid; idx < 36 * 36; idx += 256) {
        int r = idx / 36, q = idx - r * 36;
        int si = ti0 - 2 + r, sj = tj0 - 2 + q;   // level-1 coeff coords
        float c0 = 0.f, c1 = 0.f, c2 = 0.f, c3 = 0.f;
        if (si >= 0 && si < 64 && sj >= 0 && sj < 64) {
            const float* p = xb + (size_t)(4 * si) * WW + 4 * sj;
            float4 r0 = *(const float4*)p;
            float4 r1 = *(const float4*)(p + WW);
            float4 r2 = *(const float4*)(p + 2 * WW);
            float4 r3 = *(const float4*)(p + 3 * WW);
            // level-0 LL quads (unscaled sums; 0.5*0.5 folded into 0.25 below)
            float q00 = r0.x + r0.y + r1.x + r1.y;
            float q01 = r0.z + r0.w + r1.z + r1.w;
            float q10 = r2.x + r2.y + r3.x + r3.y;
            float q11 = r2.z + r2.w + r3.z + r3.w;
            float s0 = q00 + q01, d0 = q00 - q01;
            float s1 = q10 + q11, d1 = q10 - q11;
            c0 = 0.25f * (s0 + s1);
            c1 = 0.25f * (s0 - s1);   // row-sign band
            c2 = 0.25f * (d0 + d1);   // col-sign band
            c3 = 0.25f * (d0 - d1);
        }
        sb[0][r][q] = c0; sb[1][r][q] = c1; sb[2][r][q] = c2; sb[3][r][q] = c3;
    }
    __syncthreads();

    // Depthwise 5x5 + wscale: one wave per band; each thread 16 rows x 1 col
    // via 4x 4-row sliding windows. Weights in registers.
    const int k  = tid >> 6, t = tid & 63;
    const int gh = t >> 5, cx = t & 31;           // rows [16gh,16gh+16), col cx
    float wr[25];
#pragma unroll
    for (int t2 = 0; t2 < 25; ++t2) wr[t2] = wg[k][t2];
    const float wk = wsl[k];
    const size_t plane = 64 * 64;
    float* tb = tag + (size_t)bc * 4 * plane + (size_t)k * plane;

#pragma unroll
    for (int rr = 0; rr < 4; ++rr) {
        const int row0 = 16 * gh + 4 * rr;        // local output row base
        float acc[4] = {0.f, 0.f, 0.f, 0.f};
#pragma unroll
        for (int v = 0; v < 5; ++v)
#pragma unroll
            for (int i = 0; i < 8; ++i) {
                float val = sb[k][row0 + i][cx + v];
#pragma unroll
                for (int r = 0; r < 4; ++r) {
                    int u = i - r;
                    if (u >= 0 && u < 5) acc[r] += val * wr[u * 5 + v];
                }
            }
#pragma unroll
        for (int r = 0; r < 4; ++r)
            tb[(size_t)(ti0 + row0 + r) * 64 + (tj0 + cx)] = wk * acc[r];
    }

    // raw LL1 (band 0, un-convolved) for level 2
    for (int idx = tid; idx < 1024; idx += 256) {
        int r = idx >> 5, q = idx & 31;
        rawLL1[(size_t)bc * plane + (size_t)(ti0 + r) * 64 + (tj0 + q)] =
            sb[0][r + 2][q + 2];
    }
}

// ---------------------------------------------------------------------------
// fwd2: level-2 forward from rawLL1 (64x64). One block per (b,c) plane,
// 32x32 subband outputs. Staging: float4 pair-loads (2 coeffs per unit).
//   tag : (B*C, 4, 32, 32)
// ---------------------------------------------------------------------------
__global__ __launch_bounds__(256, 4) void fwd2_kernel(
    const float* __restrict__ ll,
    const float* __restrict__ wconv,
    const float* __restrict__ wsc,
    float* __restrict__ tag)
{
    const int bc  = blockIdx.x;
    const int c   = bc % CC;
    const int tid = threadIdx.x;

    __shared__ float sb[4][36][38];
    __shared__ float wg[4][25];
    __shared__ float wsl[4];

    if (tid < 100) { int k = tid / 25, t = tid % 25;
                     wg[k][t] = wconv[(c * 4 + k) * 25 + t]; }
    if (tid < 4) wsl[tid] = wsc[c * 4 + tid];

    const float* lb = ll + (size_t)bc * 4096;
    // 36 coeff rows x 18 col-pairs; pair origin sj0 = -2 + 2u (even).
    for (int idx = tid; idx < 36 * 18; idx += 256) {
        int r = idx / 18, u = idx - r * 18;
        int si = -2 + r, sj0 = -2 + 2 * u;
        float c00 = 0.f, c10 = 0.f, c20 = 0.f, c30 = 0.f;
        float c01 = 0.f, c11 = 0.f, c21 = 0.f, c31 = 0.f;
        if (si >= 0 && si < 32 && sj0 >= 0 && sj0 < 32) {
            const float* p = lb + (size_t)(2 * si) * 64 + 2 * sj0;
            float4 a = *(const float4*)p;        // row 2si,  cols 2sj0..+3
            float4 b = *(const float4*)(p + 64); // row 2si+1
            c00 = 0.5f * (a.x + a.y + b.x + b.y);
            c10 = 0.5f * (a.x + a.y - b.x - b.y);
            c20 = 0.5f * (a.x - a.y + b.x - b.y);
            c30 = 0.5f * (a.x - a.y - b.x + b.y);
            c01 = 0.5f * (a.z + a.w + b.z + b.w);
            c11 = 0.5f * (a.z + a.w - b.z - b.w);
            c21 = 0.5f * (a.z - a.w + b.z - b.w);
            c31 = 0.5f * (a.z - a.w - b.z + b.w);
        }
        int q0 = 2 * u;
        sb[0][r][q0] = c00; sb[1][r][q0] = c10;
        sb[2][r][q0] = c20; sb[3][r][q0] = c30;
        sb[0][r][q0 + 1] = c01; sb[1][r][q0 + 1] = c11;
        sb[2][r][q0 + 1] = c21; sb[3][r][q0 + 1] = c31;
    }
    __syncthreads();

    const int k  = tid >> 6, t = tid & 63;
    const int gh = t >> 5, cx = t & 31;
    float wr[25];
#pragma unroll
    for (int t2 = 0; t2 < 25; ++t2) wr[t2] = wg[k][t2];
    const float wk = wsl[k];
    float* tb = tag + (size_t)bc * 4096 + (size_t)k * 1024;

#pragma unroll
    for (int rr = 0; rr < 4; ++rr) {
        const int row0 = 16 * gh + 4 * rr;
        float acc[4] = {0.f, 0.f, 0.f, 0.f};
#pragma unroll
        for (int v = 0; v < 5; ++v)
#pragma unroll
            for (int i = 0; i < 8; ++i) {
                float val = sb[k][row0 + i][cx + v];
#pragma unroll
                for (int r = 0; r < 4; ++r) {
                    int u = i - r;
                    if (u >= 0 && u < 5) acc[r] += val * wr[u * 5 + v];
                }
            }
#pragma unroll
        for (int r = 0; r < 4; ++r)
            tb[(size_t)(row0 + r) * 32 + cx] = wk * acc[r];
    }
}

// ---------------------------------------------------------------------------
// final2: fused output kernel (structure verified last round). Changes:
//   - float4 x-tile staging (sx stride 44 for 16B alignment, 2-way banks max)
//   - conv weights copied to registers (kills LDS re-reads; VGPR was 36)
//   - __launch_bounds__(256,4) to give the allocator headroom
// ---------------------------------------------------------------------------
__global__ __launch_bounds__(256, 4) void final2_kernel(
    const float* __restrict__ x,          // (B*C, 256, 256)
    const float* __restrict__ tag1,       // (B*C, 4, 64, 64)
    const float* __restrict__ tag2,       // (B*C, 4, 32, 32)
    const float* __restrict__ wconv0,     // (512, 25) level-0
    const float* __restrict__ wsc0,       // (512)
    const float* __restrict__ base_w,     // (C, 25)
    const float* __restrict__ base_b,     // (C)
    const float* __restrict__ base_scale, // (C)
    float* __restrict__ out)              // (B*C, 256, 256)
{
    const int bc  = blockIdx.z;
    const int c   = bc % CC;
    const int tY0 = blockIdx.y * 32, tX0 = blockIdx.x * 32;
    const int tid = threadIdx.x;

    __shared__ float sx[40][44];        // x tile, origin (tY0-4, tX0-4)
    __shared__ float scf[4][20][22];    // level-0 coeff halo tile
    __shared__ float scv[4][16][17];    // wscale*conv output per band
    __shared__ float sll1[16][17];      // upsampled LL from level 1
    __shared__ float st1[4][8][9];      // tag1 tile
    __shared__ float sll2[8][9];        // upsampled LL from level 2
    __shared__ float wb[25];
    __shared__ float w0[4][25];
    __shared__ float wsl[4];
    __shared__ float sbias, sscale;

    // ---- loads ----
    if (tid < 25) wb[tid] = base_w[c * 25 + tid];
    if (tid >= 32 && tid < 132) {
        int t = tid - 32;
        w0[t / 25][t % 25] = wconv0[(c * 4 + t / 25) * 25 + t % 25];
    }
    if (tid >= 160 && tid < 164) wsl[tid - 160] = wsc0[c * 4 + (tid - 160)];
    if (tid == 255) { sbias = base_b[c]; sscale = base_scale[c]; }

    // x tile as float4 units: 40 rows x 10 units. X0 = tX0-4+4*q4 is 4-aligned
    // so every unit is fully in-range or fully out (no scalar fallback).
    const float* xb = x + (size_t)bc * (HH * WW);
    for (int idx = tid; idx < 400; idx += 256) {
        int r = idx / 10, q4 = idx - r * 10;
        int Y = tY0 - 4 + r, X0 = tX0 - 4 + 4 * q4;
        float4 v = make_float4(0.f, 0.f, 0.f, 0.f);
        if (Y >= 0 && Y < HH && X0 >= 0 && X0 < WW)
            v = *(const float4*)(xb + (size_t)Y * WW + X0);
        *(float4*)&sx[r][4 * q4] = v;
    }

    const int t1r0 = tY0 >> 2, t1c0 = tX0 >> 2;   // tag1 tile origin (64x64)
    const float* t1b = tag1 + (size_t)bc * 4 * 4096;
    {
        int k = tid >> 6, t = tid & 63, r = t >> 3, q = t & 7;
        st1[k][r][q] = t1b[k * 4096 + (t1r0 + r) * 64 + (t1c0 + q)];
    }

    // iwt2 directly from global (tiny, cache-resident): ll2up 8x8 tile
    const int t2r0 = tY0 >> 3, t2c0 = tX0 >> 3;   // tag2 tile origin (32x32)
    const float* t2b = tag2 + (size_t)bc * 4 * 1024;
    if (tid < 64) {
        int r = tid >> 3, q = tid & 7;
        const float* p = t2b + (t2r0 + (r >> 1)) * 32 + (t2c0 + (q >> 1));
        float d0 = p[0], d1 = p[1024], d2 = p[2048], d3 = p[3072];
        float ss = (r & 1) ? -1.f : 1.f, tt = (q & 1) ? -1.f : 1.f;
        sll2[r][q] = 0.5f * (d0 + ss * d1 + tt * d2 + ss * tt * d3);
    }
    __syncthreads();   // B1

    // ---- P2: level-0 Haar coeffs + iwt1 ----
    for (int idx = tid; idx < 400; idx += 256) {
        int r = idx / 20, q = idx - r * 20;
        float x00 = sx[2 * r][2 * q],     x01 = sx[2 * r][2 * q + 1];
        float x10 = sx[2 * r + 1][2 * q], x11 = sx[2 * r + 1][2 * q + 1];
        scf[0][r][q] = 0.5f * (x00 + x01 + x10 + x11);
        scf[1][r][q] = 0.5f * (x00 + x01 - x10 - x11);
        scf[2][r][q] = 0.5f * (x00 - x01 + x10 - x11);
        scf[3][r][q] = 0.5f * (x00 - x01 - x10 + x11);
    }
    {
        int ci = tid >> 4, cj = tid & 15;
        int a = ci >> 1, b = cj >> 1;
        float e0 = st1[0][a][b] + sll2[a][b];
        float e1 = st1[1][a][b], e2 = st1[2][a][b], e3 = st1[3][a][b];
        float ss = (ci & 1) ? -1.f : 1.f, tt = (cj & 1) ? -1.f : 1.f;
        sll1[ci][cj] = 0.5f * (e0 + ss * e1 + tt * e2 + ss * tt * e3);
    }
    __syncthreads();   // B2

    // ---- P3a: band convs (4 consecutive rows/thread, sliding window) ----
    {
        int k = tid >> 6, t = tid & 63, g = t >> 4, cx = t & 15;
        float wr[25];
#pragma unroll
        for (int t2 = 0; t2 < 25; ++t2) wr[t2] = w0[k][t2];
        float accb[4] = {0.f, 0.f, 0.f, 0.f};
#pragma unroll
        for (int v = 0; v < 5; ++v)
#pragma unroll
            for (int i = 0; i < 8; ++i) {
                float val = scf[k][4 * g + i][cx + v];
#pragma unroll
                for (int r = 0; r < 4; ++r) {
                    int u = i - r;
                    if (u >= 0 && u < 5) accb[r] += val * wr[u * 5 + v];
                }
            }
        float wk = wsl[k];
#pragma unroll
        for (int r = 0; r < 4; ++r) scv[k][4 * g + r][cx] = wk * accb[r];
    }

    // ---- P3b: base conv into registers (4 consecutive rows/thread) ----
    const int ty = tid >> 5, tx = tid & 31;       // 8 x 32, rows 4*ty..4*ty+3
    float wbr[25];
#pragma unroll
    for (int t2 = 0; t2 < 25; ++t2) wbr[t2] = wb[t2];
    float accx[4] = {0.f, 0.f, 0.f, 0.f};
#pragma unroll
    for (int v = 0; v < 5; ++v)
#pragma unroll
        for (int i = 0; i < 8; ++i) {
            float val = sx[4 * ty + i + 2][tx + v + 2];
#pragma unroll
            for (int r = 0; r < 4; ++r) {
                int u = i - r;
                if (u >= 0 && u < 5) accx[r] += val * wbr[u * 5 + v];
            }
        }
    __syncthreads();   // B3

    // ---- P4: iwt0 + combine + store ----
    float* ob = out + (size_t)bc * (HH * WW);
    const int Ybase = tY0 + 4 * ty;
    const int cx = tx >> 1;
    const float sbn = (tx & 1) ? -1.f : 1.f;
#pragma unroll
    for (int half = 0; half < 2; ++half) {
        int cy = 2 * ty + half;
        float c0 = scv[0][cy][cx] + sll1[cy][cx];
        float c1 = scv[1][cy][cx];
        float c2 = scv[2][cy][cx];
        float c3 = scv[3][cy][cx];
        float e = c0 + sbn * c2;
        float o = c1 + sbn * c3;
        float w_even = 0.5f * (e + o);
        float w_odd  = 0.5f * (e - o);
        int r0 = 2 * half;
        ob[(size_t)(Ybase + r0) * WW + tX0 + tx] =
            sscale * (accx[r0] + sbias) + w_even;
        ob[(size_t)(Ybase + r0 + 1) * WW + tX0 + tx] =
            sscale * (accx[r0 + 1] + sbias) + w_odd;
    }
}

// ---------------------------------------------------------------------------
extern "C" void kernel_launch(void* const* d_in, const int* in_sizes, int n_in,
                              void* d_out, int out_size, void* d_ws, size_t ws_size,
                              hipStream_t stream)
{
    const float* x          = (const float*)d_in[0];
    // d_in[1] wt_filter, d_in[2] iwt_filter: fixed Haar, hard-coded above.
    const float* base_w     = (const float*)d_in[3];
    const float* base_b     = (const float*)d_in[4];
    const float* base_scale = (const float*)d_in[5];
    const float* wconv      = (const float*)d_in[6];  // (3, 512, 25)
    const float* wscale     = (const float*)d_in[7];  // (3, 512)
    float* out = (float*)d_out;
    float* ws  = (float*)d_ws;

    // Workspace layout (floats):
    float* tag1   = ws;                  // 8*128*4*64*64 = 16,777,216
    float* rawLL1 = ws + 16777216;       // 8*128*64*64   =  4,194,304
    float* tag2   = ws + 20971520;       // 8*128*4*32*32 =  4,194,304
    // total 25,165,824 floats = 96 MiB

    const dim3 blk(256);
    const int BC = BB * CC;

    // Level 1 directly from x (two fused Haar levels in staging).
    fwd1_fused_kernel<<<dim3(2, 2, BC), blk, 0, stream>>>(
        x, wconv + 512 * 25, wscale + 512, tag1, rawLL1);

    // Level 2 from rawLL1.
    fwd2_kernel<<<dim3(BC), blk, 0, stream>>>(
        rawLL1, wconv + 2 * 512 * 25, wscale + 2 * 512, tag2);

    // Fully fused: level-0 fwd recompute + iwt2 + iwt1 + iwt0 + base conv.
    final2_kernel<<<dim3(8, 8, BC), blk, 0, stream>>>(
        x, tag1, tag2, wconv, wscale, base_w, base_b, base_scale, out);
}